// Round 3
// baseline (925.044 us; speedup 1.0000x reference)
//
#include <hip/hip_runtime.h>
#include <hip/hip_bf16.h>

// ---------------- problem constants ----------------
constexpr int BATCH = 8;
constexpr int CIN   = 256;
constexpr int HH    = 64;
constexpr int WW    = 64;
constexpr int NPIX  = HH * WW;        // 4096
constexpr int ICH   = 128;            // init_ch == new_ch
constexpr int NPASS = 40;             // 5 "experts" (4 routed + 1 shared) * 8 batches
constexpr int MAXACT = 24;            // B*(top_k+1) = 8*3

// ---------------- workspace layout (in floats) ----------------
constexpr size_t OFF_XD    = 0;                                   // 8*256*16*16 = 524288
constexpr size_t OFF_HMEAN = OFF_XD + (size_t)BATCH * CIN * 256;  // 256
constexpr size_t OFF_WFULL = OFF_HMEAN + 256;                     // 8*5 padded to 64
constexpr size_t OFF_SLOT  = OFF_WFULL + 64;                      // 40 ints padded to 64
constexpr size_t OFF_WT    = OFF_SLOT + 64;                       // 5*256*9*128 = 1474560
constexpr size_t OFF_X1    = OFF_WT + (size_t)5 * CIN * 9 * ICH;  // 24*128*4096 = 12582912
// total ~= 14.6M floats ~= 58.3 MB of d_ws

__device__ __forceinline__ float silu_f(float v) { return v / (1.f + __expf(-v)); }

// ---------------- K1: 4x4 avg pool  x[8,256,64,64] -> xd[8,256,16,16] ----------------
__global__ void k_avgpool(const float* __restrict__ x, float* __restrict__ xd)
{
    int t = blockIdx.x * 256 + threadIdx.x;        // 131072 threads, 4 outputs each
    int jb = t & 3, i = (t >> 2) & 15, c = (t >> 6) & 255, b = t >> 14;
    const float* src = x + ((size_t)(b * CIN + c) * HH + i * 4) * WW + jb * 16;
    float s0 = 0.f, s1 = 0.f, s2 = 0.f, s3 = 0.f;
#pragma unroll
    for (int r = 0; r < 4; ++r) {
        const float4* p = (const float4*)(src + r * WW);
        float4 a = p[0], b4 = p[1], c4 = p[2], d4 = p[3];
        s0 += a.x + a.y + a.z + a.w;
        s1 += b4.x + b4.y + b4.z + b4.w;
        s2 += c4.x + c4.y + c4.z + c4.w;
        s3 += d4.x + d4.y + d4.z + d4.w;
    }
    float4 o;
    o.x = s0 * 0.0625f; o.y = s1 * 0.0625f; o.z = s2 * 0.0625f; o.w = s3 * 0.0625f;
    *(float4*)(xd + ((size_t)(b * CIN + c) * 16 + i) * 16 + jb * 4) = o;
}

// ---------------- K2: router conv3x3 (256->32) + BN + SiLU, reduced to mean over HW ----
// one block per (b, r); writes hmean[b*32+r] directly (no atomics)
__global__ __launch_bounds__(256) void k_router_conv(
    const float* __restrict__ xd, const float* __restrict__ Wr1,
    const float* __restrict__ sr1, const float* __restrict__ br1,
    float* __restrict__ hmean)
{
    int b = blockIdx.x >> 5, r = blockIdx.x & 31;
    __shared__ float wl[9 * 256];   // [tap][cin] for contiguous inner reads
    __shared__ float red[256];
    int tid = threadIdx.x;
    for (int k = tid; k < 2304; k += 256) {
        int cin = k / 9, tap = k % 9;
        wl[tap * 256 + cin] = Wr1[r * 2304 + k];
    }
    __syncthreads();
    const float* xb = xd + (size_t)b * CIN * 256;
    int i = tid >> 4, j = tid & 15;
    float acc = 0.f;
#pragma unroll
    for (int kh = 0; kh < 3; ++kh) {
        int ii = i + kh - 1;
        bool oki = (unsigned)ii < 16u;
        int iis = oki ? ii : 0;
#pragma unroll
        for (int kw = 0; kw < 3; ++kw) {
            int jj = j + kw - 1;
            bool ok = oki && ((unsigned)jj < 16u);
            int off = iis * 16 + (((unsigned)jj < 16u) ? jj : 0);
            const float* wt = wl + (kh * 3 + kw) * 256;
            float t = 0.f;
#pragma unroll 8
            for (int cin = 0; cin < 256; ++cin)
                t = fmaf(wt[cin], xb[cin * 256 + off], t);
            if (ok) acc += t;
        }
    }
    float h = silu_f(acc * sr1[r] + br1[r]);
    red[tid] = h;
    __syncthreads();
    for (int st = 128; st > 0; st >>= 1) {
        if (tid < st) red[tid] += red[tid + st];
        __syncthreads();
    }
    if (tid == 0) hmean[b * 32 + r] = red[0] * (1.f / 256.f);
}

// ---------------- K3: 1x1 conv on hmean + BN, softmax, top-k, pass compaction --------
__global__ void k_router_final(const float* __restrict__ hmean,
                               const float* __restrict__ Wr2, const float* __restrict__ sr2,
                               const float* __restrict__ br2, const int* __restrict__ topk_p,
                               float* __restrict__ wfull, int* __restrict__ slot)
{
    __shared__ float lg[8][4];
    __shared__ float wf[8][5];
    int tid = threadIdx.x;
    if (tid < 32) {
        int b = tid >> 2, e = tid & 3;
        float a = 0.f;
        for (int r = 0; r < 32; ++r) a += Wr2[e * 32 + r] * hmean[b * 32 + r];
        lg[b][e] = a * sr2[e] + br2[e];
    }
    __syncthreads();
    if (tid < 8) {
        int b = tid;
        float l0 = lg[b][0], l1 = lg[b][1], l2 = lg[b][2], l3 = lg[b][3];
        float mx = fmaxf(fmaxf(l0, l1), fmaxf(l2, l3));
        float e0 = __expf(l0 - mx), e1 = __expf(l1 - mx), e2 = __expf(l2 - mx), e3 = __expf(l3 - mx);
        float sum = e0 + e1 + e2 + e3;
        float w[4] = { e0 / sum, e1 / sum, e2 / sum, e3 / sum };
        int k = topk_p[0];
        if (k > 4) k = 4;
        bool taken[4] = { false, false, false, false };
        float tv[4]; int ti[4]; float tsum = 0.f;
        for (int t = 0; t < k; ++t) {
            float best = -1e30f; int bi = 0;
            for (int e = 0; e < 4; ++e)
                if (!taken[e] && w[e] > best) { best = w[e]; bi = e; }
            taken[bi] = true; tv[t] = best; ti[t] = bi; tsum += best;
        }
        float inv = 1.f / (tsum + 1e-6f);
        float o[4] = { 0.f, 0.f, 0.f, 0.f };
        for (int t = 0; t < k; ++t) o[ti[t]] = tv[t] * inv;
        for (int e = 0; e < 4; ++e) { wf[b][e] = o[e]; wfull[b * 5 + e] = o[e]; }
        wf[b][4] = 1.f; wfull[b * 5 + 4] = 1.f;
    }
    __syncthreads();
    if (tid == 0) {
        int cnt = 0;
        for (int s = 0; s < 5; ++s)
            for (int b = 0; b < 8; ++b)
                slot[s * 8 + b] = (wf[b][s] != 0.f) ? (cnt++) : -1;
    }
}

// ---------------- Kprep: weight re-layout OIHW -> [s][cin][tap][oc] ------------------
__global__ void k_wprep(const float* __restrict__ We_p, const float* __restrict__ Ws_p,
                        float* __restrict__ wt)
{
    int t = blockIdx.x * 256 + threadIdx.x;   // 1,474,560 = 5*256*9*128, dest-linear
    int s  = t / 294912;
    int r  = t % 294912;
    int ic = r / 1152;
    int r2 = r % 1152;
    int tap = r2 >> 7;
    int oc  = r2 & 127;
    float v = (s < 4) ? We_p[s * 294912 + oc * 2304 + ic * 9 + tap]
                      : Ws_p[oc * 2304 + ic * 9 + tap];
    wt[t] = v;
}

// ---------------- K4: primary conv 3x3 (256->128) + BN + SiLU, active passes only ----
// tile: 128 och x (16w x 8h) px per block; thread tile 8 och x 8 px (one row segment)
__global__ __launch_bounds__(256, 3) void k_primary(
    const float* __restrict__ x, const float* __restrict__ wt,
    const float* __restrict__ se_p, const float* __restrict__ be_p,
    const float* __restrict__ ss_p, const float* __restrict__ bs_p,
    const int* __restrict__ slot, float* __restrict__ x1)
{
    constexpr int CK = 8;
    int pass = blockIdx.y;                 // 0..39
    int sl = slot[pass];
    if (sl < 0) return;
    int s = pass >> 3, b = pass & 7;

    int tile = blockIdx.x;                 // 0..31
    int ty = tile >> 2, tx = tile & 3;
    int i0 = ty * 8, j0 = tx * 16;

    __shared__ float xs[CK][10][20];       // x tile + halo, padded stride
    __shared__ float wsh[CK][9][128];      // [cin][tap][oc]

    int tid = threadIdx.x;
    int og = tid >> 4;                     // 0..15 -> oc = og*8..og*8+7
    int pg = tid & 15;                     // wave: 4 og x 16 pg -> weight reads broadcast
    int orow = pg >> 1;                    // 0..7
    int seg  = (pg & 1) * 8;               // 0 or 8

    const float* scale = (s < 4) ? (se_p + s * ICH) : ss_p;
    const float* shift = (s < 4) ? (be_p + s * ICH) : bs_p;
    const float* wbase = wt + (size_t)s * (CIN * 9 * ICH);
    const float* xb    = x + (size_t)b * CIN * NPIX;

    float acc[8][8];
#pragma unroll
    for (int o = 0; o < 8; ++o)
#pragma unroll
        for (int j = 0; j < 8; ++j) acc[o][j] = 0.f;

    for (int c0 = 0; c0 < CIN; c0 += CK) {
        // x chunk: CK x 10 x 18 (zero-padded halo)
        for (int k = tid; k < CK * 10 * 18; k += 256) {
            int c = k / 180, rem = k % 180, rr = rem / 18, cc = rem % 18;
            int gi = i0 - 1 + rr, gj = j0 - 1 + cc;
            float v = 0.f;
            if (gi >= 0 && gi < HH && gj >= 0 && gj < WW)
                v = xb[(size_t)(c0 + c) * NPIX + gi * WW + gj];
            xs[c][rr][cc] = v;
        }
        // weight chunk: contiguous copy (already in [cin][tap][oc] layout)
        {
            const float4* wsrc = (const float4*)(wbase + (size_t)c0 * 9 * ICH);
            float4* wdst = (float4*)&wsh[0][0][0];
            for (int k = tid; k < CK * 9 * ICH / 4; k += 256) wdst[k] = wsrc[k];
        }
        __syncthreads();
#pragma unroll 1
        for (int c = 0; c < CK; ++c) {
#pragma unroll
            for (int kh = 0; kh < 3; ++kh) {
                float xr[10];
#pragma unroll
                for (int t = 0; t < 10; ++t) xr[t] = xs[c][orow + kh][seg + t];
#pragma unroll
                for (int kw = 0; kw < 3; ++kw) {
                    float wv[8];
#pragma unroll
                    for (int o = 0; o < 8; ++o) wv[o] = wsh[c][kh * 3 + kw][og * 8 + o];
#pragma unroll
                    for (int o = 0; o < 8; ++o)
#pragma unroll
                        for (int j = 0; j < 8; ++j)
                            acc[o][j] = fmaf(wv[o], xr[j + kw], acc[o][j]);
                }
            }
        }
        __syncthreads();
    }

    // epilogue: BN + SiLU, store x1 (unweighted; weighting happens in combine)
    float* outp = x1 + (size_t)sl * (ICH * NPIX);
    int gi = i0 + orow, gj = j0 + seg;
#pragma unroll
    for (int o = 0; o < 8; ++o) {
        int oc = og * 8 + o;
        float sc = scale[oc], sh = shift[oc];
        float vals[8];
#pragma unroll
        for (int j = 0; j < 8; ++j) {
            float v = acc[o][j] * sc + sh;
            vals[j] = silu_f(v);
        }
        float4* dst = (float4*)(outp + (size_t)oc * NPIX + gi * WW + gj);
        dst[0] = make_float4(vals[0], vals[1], vals[2], vals[3]);
        dst[1] = make_float4(vals[4], vals[5], vals[6], vals[7]);
    }
}

// ---------------- K5: depthwise 3x3 + BN + SiLU + weighted combine -> out ------------
// one block per (b, c); iterates active passes s=0..4, accumulates both output halves
__global__ __launch_bounds__(256) void k_cheap(
    const float* __restrict__ x1, const float* __restrict__ We_c,
    const float* __restrict__ se_c, const float* __restrict__ be_c,
    const float* __restrict__ Ws_c, const float* __restrict__ ss_c,
    const float* __restrict__ bs_c, const float* __restrict__ wfull,
    const int* __restrict__ slot, float* __restrict__ out)
{
    int blk = blockIdx.x;
    int b = blk >> 7, c = blk & 127;
    __shared__ float img[66][66];
    int tid = threadIdx.x;
    for (int k = tid; k < 66 * 66; k += 256) ((float*)img)[k] = 0.f;  // borders stay 0
    float o1[16], o2[16];
#pragma unroll
    for (int t = 0; t < 16; ++t) { o1[t] = 0.f; o2[t] = 0.f; }
    __syncthreads();

    for (int s = 0; s < 5; ++s) {
        int sl = slot[s * 8 + b];
        if (sl < 0) continue;                       // block-uniform
        float wgt = (s < 4) ? wfull[b * 5 + s] : 1.0f;
        const float* src = x1 + ((size_t)sl * ICH + c) * NPIX;
        for (int k = tid; k < NPIX; k += 256) img[1 + (k >> 6)][1 + (k & 63)] = src[k];
        float wc[9], sc, sh;
        if (s < 4) {
            const float* wp = We_c + (size_t)(s * ICH + c) * 9;
#pragma unroll
            for (int t = 0; t < 9; ++t) wc[t] = wp[t];
            sc = se_c[s * ICH + c]; sh = be_c[s * ICH + c];
        } else {
            const float* wp = Ws_c + (size_t)c * 9;
#pragma unroll
            for (int t = 0; t < 9; ++t) wc[t] = wp[t];
            sc = ss_c[c]; sh = bs_c[c];
        }
        __syncthreads();
#pragma unroll
        for (int t = 0; t < 16; ++t) {
            int p = tid + t * 256;
            int i = p >> 6, j = p & 63;
            float center = img[1 + i][1 + j];
            float d = 0.f;
#pragma unroll
            for (int kh = 0; kh < 3; ++kh)
#pragma unroll
                for (int kw = 0; kw < 3; ++kw)
                    d = fmaf(wc[kh * 3 + kw], img[i + kh][j + kw], d);
            float v = d * sc + sh;
            o1[t] += wgt * center;
            o2[t] += wgt * silu_f(v);
        }
        __syncthreads();
    }

    float* out1 = out + ((size_t)(b * 256) + c) * NPIX;
    float* out2 = out + ((size_t)(b * 256) + 128 + c) * NPIX;
#pragma unroll
    for (int t = 0; t < 16; ++t) {
        int p = tid + t * 256;
        out1[p] = o1[t];
        out2[p] = o2[t];
    }
}

// ---------------- launcher ----------------
extern "C" void kernel_launch(void* const* d_in, const int* in_sizes, int n_in,
                              void* d_out, int out_size, void* d_ws, size_t ws_size,
                              hipStream_t stream)
{
    const float* x    = (const float*)d_in[0];
    const float* Wr1  = (const float*)d_in[1];
    const float* sr1  = (const float*)d_in[2];
    const float* br1  = (const float*)d_in[3];
    const float* Wr2  = (const float*)d_in[4];
    const float* sr2  = (const float*)d_in[5];
    const float* br2  = (const float*)d_in[6];
    const float* We_p = (const float*)d_in[7];
    const float* se_p = (const float*)d_in[8];
    const float* be_p = (const float*)d_in[9];
    const float* We_c = (const float*)d_in[10];
    const float* se_c = (const float*)d_in[11];
    const float* be_c = (const float*)d_in[12];
    const float* Ws_p = (const float*)d_in[13];
    const float* ss_p = (const float*)d_in[14];
    const float* bs_p = (const float*)d_in[15];
    const float* Ws_c = (const float*)d_in[16];
    const float* ss_c = (const float*)d_in[17];
    const float* bs_c = (const float*)d_in[18];
    const int*  topk  = (const int*)d_in[19];
    float* out = (float*)d_out;
    float* ws  = (float*)d_ws;

    float* xd    = ws + OFF_XD;
    float* hmean = ws + OFF_HMEAN;
    float* wfull = ws + OFF_WFULL;
    int*   slot  = (int*)(ws + OFF_SLOT);
    float* wt    = ws + OFF_WT;
    float* x1    = ws + OFF_X1;
    // requires ws_size >= ~59 MB (58.3 MB used)

    k_avgpool<<<512, 256, 0, stream>>>(x, xd);
    k_router_conv<<<256, 256, 0, stream>>>(xd, Wr1, sr1, br1, hmean);
    k_router_final<<<1, 64, 0, stream>>>(hmean, Wr2, sr2, br2, topk, wfull, slot);
    k_wprep<<<5760, 256, 0, stream>>>(We_p, Ws_p, wt);
    k_primary<<<dim3(32, 40), 256, 0, stream>>>(x, wt, se_p, be_p, ss_p, bs_p, slot, x1);
    k_cheap<<<1024, 256, 0, stream>>>(x1, We_c, se_c, be_c, Ws_c, ss_c, bs_c, wfull, slot, out);
}

// Round 5
// 315.398 us; speedup vs baseline: 2.9329x; 2.9329x over previous
//
#include <hip/hip_runtime.h>
#include <hip/hip_bf16.h>

// ---------------- problem constants ----------------
constexpr int BATCH = 8;
constexpr int CIN   = 256;
constexpr int HH    = 64;
constexpr int WW    = 64;
constexpr int NPIX  = HH * WW;        // 4096
constexpr int ICH   = 128;            // init_ch == new_ch

// ---------------- workspace layout (in floats) ----------------
constexpr size_t OFF_XD    = 0;                        // 8*256*16*16 = 524288 f
constexpr size_t OFF_HMEAN = 524288;                   // 256 f
constexpr size_t OFF_WFULL = 524544;                   // 64 f
constexpr size_t OFF_SLOT  = 524608;                   // 64 f (ints)
constexpr size_t OFF_WTB   = 524672;                   // bf16 weights: 1,474,560 us = 737,280 f
constexpr size_t OFF_XB    = OFF_WTB + 737280;         // bf16 x NHWC: 8,388,608 us = 4,194,304 f
constexpr size_t OFF_X1B   = OFF_XB + 4194304;         // bf16 x1: 24*128*4096 us = 6,291,456 f
// total = 11,747,712 floats = 47.0 MB of d_ws (round-3 watermark was 58.3 MB: safe)

typedef __bf16  bf16x8 __attribute__((ext_vector_type(8)));
typedef float   f32x4  __attribute__((ext_vector_type(4)));

__device__ __forceinline__ float silu_f(float v) { return v / (1.f + __expf(-v)); }

__device__ __forceinline__ unsigned short f2bf(float f) {
    return __builtin_bit_cast(unsigned short, __float2bfloat16(f));
}
__device__ __forceinline__ float bf2f(unsigned short u) {
    return __builtin_bit_cast(float, (unsigned)u << 16);
}
__device__ __forceinline__ bf16x8 ld_frag(const ushort* p) {
    uint4 v = *(const uint4*)p;          // ds_read_b128
    return __builtin_bit_cast(bf16x8, v);
}

// ---------------- K1: 4x4 avg pool  x[8,256,64,64] -> xd[8,256,16,16] ----------------
__global__ void k_avgpool(const float* __restrict__ x, float* __restrict__ xd)
{
    int t = blockIdx.x * 256 + threadIdx.x;
    int jb = t & 3, i = (t >> 2) & 15, c = (t >> 6) & 255, b = t >> 14;
    const float* src = x + ((size_t)(b * CIN + c) * HH + i * 4) * WW + jb * 16;
    float s0 = 0.f, s1 = 0.f, s2 = 0.f, s3 = 0.f;
#pragma unroll
    for (int r = 0; r < 4; ++r) {
        const float4* p = (const float4*)(src + r * WW);
        float4 a = p[0], b4 = p[1], c4 = p[2], d4 = p[3];
        s0 += a.x + a.y + a.z + a.w;
        s1 += b4.x + b4.y + b4.z + b4.w;
        s2 += c4.x + c4.y + c4.z + c4.w;
        s3 += d4.x + d4.y + d4.z + d4.w;
    }
    float4 o;
    o.x = s0 * 0.0625f; o.y = s1 * 0.0625f; o.z = s2 * 0.0625f; o.w = s3 * 0.0625f;
    *(float4*)(xd + ((size_t)(b * CIN + c) * 16 + i) * 16 + jb * 4) = o;
}

// ---------------- K1b: x fp32 NCHW -> bf16 NHWC [b][row][col][cin] ------------------
__global__ __launch_bounds__(256) void k_xprep(const float* __restrict__ x,
                                               ushort* __restrict__ xb)
{
    int b = blockIdx.x >> 6, row = blockIdx.x & 63;
    __shared__ ushort tile[64 * 258];    // [col][cin], pad 2 to break bank conflicts
    int tid = threadIdx.x;
    const float* src = x + ((size_t)b * CIN * HH + row) * WW;   // + cin*4096 + col
    for (int k = tid; k < 256 * 64; k += 256) {
        int cin = k >> 6, col = k & 63;                         // coalesced fp32 read
        tile[col * 258 + cin] = f2bf(src[(size_t)cin * NPIX + col]);
    }
    __syncthreads();
    ushort* dst = xb + (size_t)(b * 64 + row) * 64 * 256;
    for (int k = tid; k < 64 * 128; k += 256) {
        int col = k >> 7, cp = (k & 127) * 2;
        unsigned u0 = tile[col * 258 + cp];
        unsigned u1 = tile[col * 258 + cp + 1];
        *(unsigned*)(dst + (size_t)col * 256 + cp) = u0 | (u1 << 16);  // coalesced
    }
}

// ---------------- K2: router conv3x3 (256->32) + BN + SiLU, mean over HW -------------
__global__ __launch_bounds__(256) void k_router_conv(
    const float* __restrict__ xd, const float* __restrict__ Wr1,
    const float* __restrict__ sr1, const float* __restrict__ br1,
    float* __restrict__ hmean)
{
    int b = blockIdx.x >> 5, r = blockIdx.x & 31;
    __shared__ float wl[9 * 256];
    __shared__ float red[256];
    int tid = threadIdx.x;
    for (int k = tid; k < 2304; k += 256) {
        int cin = k / 9, tap = k % 9;
        wl[tap * 256 + cin] = Wr1[r * 2304 + k];
    }
    __syncthreads();
    const float* xb = xd + (size_t)b * CIN * 256;
    int i = tid >> 4, j = tid & 15;
    float acc = 0.f;
#pragma unroll
    for (int kh = 0; kh < 3; ++kh) {
        int ii = i + kh - 1;
        bool oki = (unsigned)ii < 16u;
        int iis = oki ? ii : 0;
#pragma unroll
        for (int kw = 0; kw < 3; ++kw) {
            int jj = j + kw - 1;
            bool ok = oki && ((unsigned)jj < 16u);
            int off = iis * 16 + (((unsigned)jj < 16u) ? jj : 0);
            const float* wt = wl + (kh * 3 + kw) * 256;
            float t = 0.f;
#pragma unroll 8
            for (int cin = 0; cin < 256; ++cin)
                t = fmaf(wt[cin], xb[cin * 256 + off], t);
            if (ok) acc += t;
        }
    }
    float h = silu_f(acc * sr1[r] + br1[r]);
    red[tid] = h;
    __syncthreads();
    for (int st = 128; st > 0; st >>= 1) {
        if (tid < st) red[tid] += red[tid + st];
        __syncthreads();
    }
    if (tid == 0) hmean[b * 32 + r] = red[0] * (1.f / 256.f);
}

// ---------------- K3: router head: 1x1 conv + BN, softmax, top-k, slot compaction ----
__global__ void k_router_final(const float* __restrict__ hmean,
                               const float* __restrict__ Wr2, const float* __restrict__ sr2,
                               const float* __restrict__ br2, const int* __restrict__ topk_p,
                               float* __restrict__ wfull, int* __restrict__ slot)
{
    __shared__ float lg[8][4];
    __shared__ float wf[8][5];
    int tid = threadIdx.x;
    if (tid < 32) {
        int b = tid >> 2, e = tid & 3;
        float a = 0.f;
        for (int r = 0; r < 32; ++r) a += Wr2[e * 32 + r] * hmean[b * 32 + r];
        lg[b][e] = a * sr2[e] + br2[e];
    }
    __syncthreads();
    if (tid < 8) {
        int b = tid;
        float l0 = lg[b][0], l1 = lg[b][1], l2 = lg[b][2], l3 = lg[b][3];
        float mx = fmaxf(fmaxf(l0, l1), fmaxf(l2, l3));
        float e0 = __expf(l0 - mx), e1 = __expf(l1 - mx), e2 = __expf(l2 - mx), e3 = __expf(l3 - mx);
        float sum = e0 + e1 + e2 + e3;
        float w[4] = { e0 / sum, e1 / sum, e2 / sum, e3 / sum };
        int k = topk_p[0];
        if (k > 4) k = 4;
        bool taken[4] = { false, false, false, false };
        float tv[4]; int ti[4]; float tsum = 0.f;
        for (int t = 0; t < k; ++t) {
            float best = -1e30f; int bi = 0;
            for (int e = 0; e < 4; ++e)
                if (!taken[e] && w[e] > best) { best = w[e]; bi = e; }
            taken[bi] = true; tv[t] = best; ti[t] = bi; tsum += best;
        }
        float inv = 1.f / (tsum + 1e-6f);
        float o[4] = { 0.f, 0.f, 0.f, 0.f };
        for (int t = 0; t < k; ++t) o[ti[t]] = tv[t] * inv;
        for (int e = 0; e < 4; ++e) { wf[b][e] = o[e]; wfull[b * 5 + e] = o[e]; }
        wf[b][4] = 1.f; wfull[b * 5 + 4] = 1.f;
    }
    __syncthreads();
    if (tid == 0) {
        int cnt = 0;
        for (int s = 0; s < 5; ++s)
            for (int b = 0; b < 8; ++b)
                slot[s * 8 + b] = (wf[b][s] != 0.f) ? (cnt++) : -1;
    }
}

// ---------------- Kprep: weights fp32 OIHW -> bf16 [s][half][chunk][tap][oc64][ks][8] -
__global__ void k_wprep16(const float* __restrict__ We_p, const float* __restrict__ Ws_p,
                          ushort* __restrict__ wtb)
{
    int t = blockIdx.x * 256 + threadIdx.x;   // 1,474,560 dest-linear
    int k5  = t & 31;                          // ks*8+j = cin-in-chunk
    int oc  = (t >> 5) & 63;
    int tap = (t >> 11) % 9;
    int blk = t / 18432;                       // s*16 + h*8 + chunk
    int chunk = blk & 7;
    int h     = (blk >> 3) & 1;
    int s     = blk >> 4;
    int cin   = chunk * 32 + k5;
    int ocg   = h * 64 + oc;
    float v = (s < 4) ? We_p[((size_t)(s * 128 + ocg) * 256 + cin) * 9 + tap]
                      : Ws_p[((size_t)ocg * 256 + cin) * 9 + tap];
    wtb[t] = f2bf(v);
}

// ---------------- K4: primary conv 3x3 (256->128) as bf16 MFMA implicit GEMM ---------
// block: 4 waves, 64 oc x 256 px (16x16 spatial); wave: 64 oc x 64 px (4 rows)
// LDS granule = 16B of 8 cins; weights [tap][oc][ks], x-halo [row][ks][col]
__global__ __launch_bounds__(256, 2) void k_primary_mfma(
    const ushort* __restrict__ xb, const ushort* __restrict__ wtb,
    const float* __restrict__ se_p, const float* __restrict__ be_p,
    const float* __restrict__ ss_p, const float* __restrict__ bs_p,
    const int* __restrict__ slot, ushort* __restrict__ x1b)
{
    int pass = blockIdx.y;
    int sl = slot[pass];
    if (sl < 0) return;
    int s = pass >> 3, b = pass & 7;
    int och = blockIdx.x >> 4;                         // oc half: 0/1
    int tile = blockIdx.x & 15;
    int row0 = (tile >> 2) * 16, col0 = (tile & 3) * 16;

    __shared__ ushort wlds[2304 * 8];                  // 9*64*4 granules = 36864 B
    __shared__ ushort xlds[1296 * 8];                  // 18*4*18 granules = 20736 B

    int tid = threadIdx.x;
    int w = tid >> 6, l = tid & 63;
    int ks = l >> 4, c = l & 15;

    f32x4 acc[4][4];                                   // [oc frag m][row frag n]
#pragma unroll
    for (int m = 0; m < 4; ++m)
#pragma unroll
        for (int n = 0; n < 4; ++n) acc[m][n] = (f32x4){0.f, 0.f, 0.f, 0.f};

    const ushort* wslab = wtb + (size_t)(s * 2 + och) * 8 * 18432;  // per-chunk 18432 us
    const ushort* xbase = xb + (size_t)b * 64 * 64 * 256;

    for (int ch = 0; ch < 8; ++ch) {
        __syncthreads();                               // protect LDS reuse
        // ---- stage weights: linear 16B copy, 2304 granules ----
        const ushort* wsrc = wslab + ch * 18432;
        for (int k = tid; k < 2304; k += 256) {
            uint4 v = *(const uint4*)(wsrc + k * 8);
            *(uint4*)(wlds + k * 8) = v;
        }
        // ---- stage x halo: 1296 granules, zero-padded at borders ----
        int cin0 = ch * 32;
        for (int k = tid; k < 1296; k += 256) {
            int r = k / 72, rem = k % 72;
            int ks2 = rem / 18, c2 = rem % 18;
            int gr = row0 + r - 1, gc = col0 + c2 - 1;
            uint4 v = make_uint4(0u, 0u, 0u, 0u);
            if ((unsigned)gr < 64u && (unsigned)gc < 64u)
                v = *(const uint4*)(xbase + ((size_t)gr * 64 + gc) * 256 + cin0 + ks2 * 8);
            *(uint4*)(xlds + (size_t)k * 8) = v;
        }
        __syncthreads();
        // ---- compute: 9 taps x 16 mfma ----
#pragma unroll
        for (int kh = 0; kh < 3; ++kh) {
#pragma unroll
            for (int kw = 0; kw < 3; ++kw) {
                int tap = kh * 3 + kw;
                bf16x8 afr[4];
#pragma unroll
                for (int m = 0; m < 4; ++m)
                    afr[m] = ld_frag(wlds + ((size_t)(tap * 64 + m * 16 + c) * 4 + ks) * 8);
#pragma unroll
                for (int n = 0; n < 4; ++n) {
                    int rloc = 4 * w + n + kh;         // halo row 0..17
                    bf16x8 bfr = ld_frag(xlds + ((size_t)(rloc * 4 + ks) * 18 + c + kw) * 8);
#pragma unroll
                    for (int m = 0; m < 4; ++m)
                        acc[m][n] = __builtin_amdgcn_mfma_f32_16x16x32_bf16(
                            afr[m], bfr, acc[m][n], 0, 0, 0);
                }
            }
        }
    }

    // ---- epilogue: BN + SiLU, bf16 store ----
    const float* scale = (s < 4) ? (se_p + s * ICH) : ss_p;
    const float* shift = (s < 4) ? (be_p + s * ICH) : bs_p;
    ushort* outp = x1b + (size_t)sl * (ICH * NPIX);
    int colg = col0 + c;
#pragma unroll
    for (int m = 0; m < 4; ++m) {
#pragma unroll
        for (int n = 0; n < 4; ++n) {
            int rowg = row0 + 4 * w + n;
#pragma unroll
            for (int j = 0; j < 4; ++j) {
                int oc = och * 64 + m * 16 + ks * 4 + j;   // D: row=(lane>>4)*4+reg
                float v = acc[m][n][j] * scale[oc] + shift[oc];
                outp[(size_t)oc * NPIX + rowg * 64 + colg] = f2bf(silu_f(v));
            }
        }
    }
}

// ---------------- K5: depthwise 3x3 + BN + SiLU + weighted combine -> out ------------
__global__ __launch_bounds__(256) void k_cheap(
    const ushort* __restrict__ x1b, const float* __restrict__ We_c,
    const float* __restrict__ se_c, const float* __restrict__ be_c,
    const float* __restrict__ Ws_c, const float* __restrict__ ss_c,
    const float* __restrict__ bs_c, const float* __restrict__ wfull,
    const int* __restrict__ slot, float* __restrict__ out)
{
    int blk = blockIdx.x;
    int b = blk >> 7, c = blk & 127;
    __shared__ float img[66][66];
    int tid = threadIdx.x;
    for (int k = tid; k < 66 * 66; k += 256) ((float*)img)[k] = 0.f;
    float o1[16], o2[16];
#pragma unroll
    for (int t = 0; t < 16; ++t) { o1[t] = 0.f; o2[t] = 0.f; }
    __syncthreads();

    for (int s = 0; s < 5; ++s) {
        int sl = slot[s * 8 + b];
        if (sl < 0) continue;
        float wgt = (s < 4) ? wfull[b * 5 + s] : 1.0f;
        const ushort* src = x1b + ((size_t)sl * ICH + c) * NPIX;
        for (int k = tid; k < NPIX / 2; k += 256) {
            int i = k >> 5, jc = (k & 31) * 2;
            unsigned u = *(const unsigned*)(src + i * 64 + jc);
            img[1 + i][1 + jc] = bf2f((unsigned short)(u & 0xFFFFu));
            img[1 + i][2 + jc] = bf2f((unsigned short)(u >> 16));
        }
        float wc[9], sc, sh;
        if (s < 4) {
            const float* wp = We_c + (size_t)(s * ICH + c) * 9;
#pragma unroll
            for (int t = 0; t < 9; ++t) wc[t] = wp[t];
            sc = se_c[s * ICH + c]; sh = be_c[s * ICH + c];
        } else {
            const float* wp = Ws_c + (size_t)c * 9;
#pragma unroll
            for (int t = 0; t < 9; ++t) wc[t] = wp[t];
            sc = ss_c[c]; sh = bs_c[c];
        }
        __syncthreads();
#pragma unroll
        for (int t = 0; t < 16; ++t) {
            int p = tid + t * 256;
            int i = p >> 6, j = p & 63;
            float center = img[1 + i][1 + j];
            float d = 0.f;
#pragma unroll
            for (int kh = 0; kh < 3; ++kh)
#pragma unroll
                for (int kw = 0; kw < 3; ++kw)
                    d = fmaf(wc[kh * 3 + kw], img[i + kh][j + kw], d);
            float v = d * sc + sh;
            o1[t] += wgt * center;
            o2[t] += wgt * silu_f(v);
        }
        __syncthreads();
    }

    float* out1 = out + ((size_t)(b * 256) + c) * NPIX;
    float* out2 = out + ((size_t)(b * 256) + 128 + c) * NPIX;
#pragma unroll
    for (int t = 0; t < 16; ++t) {
        int p = tid + t * 256;
        out1[p] = o1[t];
        out2[p] = o2[t];
    }
}

// ---------------- launcher ----------------
extern "C" void kernel_launch(void* const* d_in, const int* in_sizes, int n_in,
                              void* d_out, int out_size, void* d_ws, size_t ws_size,
                              hipStream_t stream)
{
    const float* x    = (const float*)d_in[0];
    const float* Wr1  = (const float*)d_in[1];
    const float* sr1  = (const float*)d_in[2];
    const float* br1  = (const float*)d_in[3];
    const float* Wr2  = (const float*)d_in[4];
    const float* sr2  = (const float*)d_in[5];
    const float* br2  = (const float*)d_in[6];
    const float* We_p = (const float*)d_in[7];
    const float* se_p = (const float*)d_in[8];
    const float* be_p = (const float*)d_in[9];
    const float* We_c = (const float*)d_in[10];
    const float* se_c = (const float*)d_in[11];
    const float* be_c = (const float*)d_in[12];
    const float* Ws_p = (const float*)d_in[13];
    const float* ss_p = (const float*)d_in[14];
    const float* bs_p = (const float*)d_in[15];
    const float* Ws_c = (const float*)d_in[16];
    const float* ss_c = (const float*)d_in[17];
    const float* bs_c = (const float*)d_in[18];
    const int*  topk  = (const int*)d_in[19];
    float* out = (float*)d_out;
    float* ws  = (float*)d_ws;

    float*  xd    = ws + OFF_XD;
    float*  hmean = ws + OFF_HMEAN;
    float*  wfull = ws + OFF_WFULL;
    int*    slot  = (int*)(ws + OFF_SLOT);
    ushort* wtb   = (ushort*)(ws + OFF_WTB);
    ushort* xb16  = (ushort*)(ws + OFF_XB);
    ushort* x1b   = (ushort*)(ws + OFF_X1B);
    // requires ws_size >= 47.0 MB (under round-3's proven 58.3 MB)

    k_avgpool<<<512, 256, 0, stream>>>(x, xd);
    k_xprep<<<512, 256, 0, stream>>>(x, xb16);
    k_wprep16<<<5760, 256, 0, stream>>>(We_p, Ws_p, wtb);
    k_router_conv<<<256, 256, 0, stream>>>(xd, Wr1, sr1, br1, hmean);
    k_router_final<<<1, 64, 0, stream>>>(hmean, Wr2, sr2, br2, topk, wfull, slot);
    k_primary_mfma<<<dim3(32, 40), 256, 0, stream>>>(xb16, wtb, se_p, be_p, ss_p, bs_p, slot, x1b);
    k_cheap<<<1024, 256, 0, stream>>>(x1b, We_c, se_c, be_c, Ws_c, ss_c, bs_c, wfull, slot, out);
}